// Round 3
// baseline (232.939 us; speedup 1.0000x reference)
//
#include <hip/hip_runtime.h>

#define ROW_LEN 2048
#define V4_PER_LANE (ROW_LEN / 4 / 64)   // 8 float4 per lane per row
#define ROWS_PER_WAVE 4
#define WAVES_PER_BLOCK 4
#define BLOCK (WAVES_PER_BLOCK * 64)
#define EPS 1e-5f

typedef float vf4 __attribute__((ext_vector_type(4)));

__global__ __launch_bounds__(BLOCK) void RMSNorm_56607668961691_kernel(
    const vf4* __restrict__ x,
    const vf4* __restrict__ g,
    vf4* __restrict__ out,
    int rows)
{
    const int wave = threadIdx.x >> 6;
    const int lane = threadIdx.x & 63;
    const int gwave = blockIdx.x * WAVES_PER_BLOCK + wave;
    const int row0 = gwave * ROWS_PER_WAVE;
    if (row0 >= rows) return;

    // g is identical for every row: load once per wave, keep in registers.
    vf4 gr[V4_PER_LANE];
    #pragma unroll
    for (int k = 0; k < V4_PER_LANE; ++k)
        gr[k] = g[lane + k * 64];

    const vf4* __restrict__ xr   = x   + (size_t)row0 * (ROW_LEN / 4);
    vf4* __restrict__       outr = out + (size_t)row0 * (ROW_LEN / 4);

    // Prefetch row0
    vf4 cur[V4_PER_LANE];
    #pragma unroll
    for (int k = 0; k < V4_PER_LANE; ++k)
        cur[k] = xr[lane + k * 64];

    #pragma unroll
    for (int i = 0; i < ROWS_PER_WAVE; ++i) {
        // Issue next row's loads BEFORE the reduce, so they overlap the
        // shfl chain + store phase of the current row (vmcnt vs lgkmcnt
        // are independent counters).
        vf4 nxt[V4_PER_LANE];
        if (i + 1 < ROWS_PER_WAVE) {
            const vf4* __restrict__ xn = xr + (size_t)(i + 1) * (ROW_LEN / 4);
            #pragma unroll
            for (int k = 0; k < V4_PER_LANE; ++k)
                nxt[k] = xn[lane + k * 64];
        }

        float ss = 0.0f;
        #pragma unroll
        for (int k = 0; k < V4_PER_LANE; ++k)
            ss += cur[k].x * cur[k].x + cur[k].y * cur[k].y
                + cur[k].z * cur[k].z + cur[k].w * cur[k].w;

        #pragma unroll
        for (int off = 32; off > 0; off >>= 1)
            ss += __shfl_xor(ss, off, 64);

        const float scale = rsqrtf(ss * (1.0f / (float)ROW_LEN) + EPS);

        vf4* __restrict__ outn = outr + (size_t)i * (ROW_LEN / 4);
        #pragma unroll
        for (int k = 0; k < V4_PER_LANE; ++k) {
            vf4 o;
            o.x = cur[k].x * scale * gr[k].x;
            o.y = cur[k].y * scale * gr[k].y;
            o.z = cur[k].z * scale * gr[k].z;
            o.w = cur[k].w * scale * gr[k].w;
            outn[lane + k * 64] = o;
        }

        if (i + 1 < ROWS_PER_WAVE) {
            #pragma unroll
            for (int k = 0; k < V4_PER_LANE; ++k)
                cur[k] = nxt[k];
        }
    }
}

extern "C" void kernel_launch(void* const* d_in, const int* in_sizes, int n_in,
                              void* d_out, int out_size, void* d_ws, size_t ws_size,
                              hipStream_t stream) {
    const vf4* x = (const vf4*)d_in[0];
    const vf4* g = (const vf4*)d_in[1];
    vf4* out = (vf4*)d_out;

    const int rows = in_sizes[0] / ROW_LEN;                      // 16384
    const int waves = (rows + ROWS_PER_WAVE - 1) / ROWS_PER_WAVE; // 4096
    const int grid  = (waves + WAVES_PER_BLOCK - 1) / WAVES_PER_BLOCK; // 1024
    RMSNorm_56607668961691_kernel<<<grid, BLOCK, 0, stream>>>(x, g, out, rows);
}